// Round 11
// baseline (88.512 us; speedup 1.0000x reference)
//
#include <hip/hip_runtime.h>
#include <hip/hip_bf16.h>
#include <math.h>

#define NSPLIT 24          // divisible by 8 for the XCD swizzle; 768 blocks = 3/CU
#define MROWS  128

typedef __attribute__((ext_vector_type(8))) short short8;
typedef __attribute__((ext_vector_type(4))) float f32x4;

#define AS1 __attribute__((address_space(1)))
#define AS3 __attribute__((address_space(3)))

__device__ __forceinline__ short f2bf(float f) {
    __hip_bfloat16 h = __float2bfloat16(f);
    return __builtin_bit_cast(short, h);
}

// ---------------------------------------------------------------------------
// Preprocess:
//   X rows -> Xb bf16 (unscaled)  + Eq[col] = exp2(q*||X||^2)  (f32)
//   x rows -> xb bf16 scaled by -2q + x2q[row] = q*||x||^2     (f32)
// q = -log2(e)/(2 b^2).  exp(-d2/(2b^2)) = exp2(q*x2) * Eq[col] * exp2((-2q x)·X)
// ---------------------------------------------------------------------------
__global__ __launch_bounds__(256) void kde_prep(
    const float* __restrict__ x, const float* __restrict__ Xg,
    const float* __restrict__ bw,
    short* __restrict__ Xb, float* __restrict__ Eq,
    short* __restrict__ xb, float* __restrict__ x2q, int M, int N)
{
    const int gid = blockIdx.x * 256 + threadIdx.x;
    const int row = gid >> 3;
    const int sub = gid & 7;
    if (row >= M + N) return;

    const float b = bw[0];
    const float q = -1.4426950408889634f / (2.f * b * b);
    const float s2q = -2.f * q;

    const float* src;
    short* dst;
    float sc;
    if (row < N) { src = Xg + (size_t)row * 64;     dst = Xb + (size_t)row * 64;     sc = 1.f; }
    else         { src = x  + (size_t)(row-N) * 64; dst = xb + (size_t)(row-N) * 64; sc = s2q; }

    float4 v0 = ((const float4*)(src + sub * 8))[0];
    float4 v1 = ((const float4*)(src + sub * 8))[1];

    float ss = v0.x*v0.x + v0.y*v0.y + v0.z*v0.z + v0.w*v0.w
             + v1.x*v1.x + v1.y*v1.y + v1.z*v1.z + v1.w*v1.w;
    ss += __shfl_xor(ss, 1);
    ss += __shfl_xor(ss, 2);
    ss += __shfl_xor(ss, 4);

    short8 o;
    o[0]=f2bf(v0.x*sc); o[1]=f2bf(v0.y*sc); o[2]=f2bf(v0.z*sc); o[3]=f2bf(v0.w*sc);
    o[4]=f2bf(v1.x*sc); o[5]=f2bf(v1.y*sc); o[6]=f2bf(v1.z*sc); o[7]=f2bf(v1.w*sc);
    *(short8*)(dst + sub * 8) = o;

    if (sub == 0) {
        if (row < N) Eq[row] = exp2f(ss * q);
        else         x2q[row - N] = ss * q;
    }
}

// ---------------------------------------------------------------------------
// Main (round 11): 128 x-rows per block, 4 waves; each wave owns 16 cols/iter.
//
// B + Eq are staged into WAVE-PRIVATE LDS double-buffers with
// global_load_lds (3 vmem ops per iter per wave), and the wait is a
// HAND-COUNTED `s_waitcnt vmcnt(3)` so the next iteration's stage stays in
// flight across the compute (T3/T4 pattern). No __syncthreads in the loop.
// gload_lds writes linearly -> the seg^=(col&7) XOR-swizzle is applied on
// the per-lane GLOBAL source address; ds_read applies the same XOR.
//
// Register diet: single acc buffer, no register B/Eq buffers -> ~155 live
// regs -> 3 waves/SIMD (launch_bounds(256,3), cap 170). Grid 768 = 3
// blocks/CU exact. XCD swizzle: split=(L&7)+8*(L/(8*NB)), mblock=(L>>3)%NB.
// ---------------------------------------------------------------------------
__global__ __launch_bounds__(256, 3) void kde_main10(
    const short* __restrict__ Xb, const float* __restrict__ Eq,
    const short* __restrict__ xb,
    float* __restrict__ partial, int M, int N, int NB)
{
    const int tid  = threadIdx.x;
    const int lane = tid & 63;
    const int wave = tid >> 6;
    const int l15  = lane & 15;
    const int kq   = lane >> 4;

    const int L      = blockIdx.x;
    const int split  = (L & 7) + 8 * (L / (8 * NB));
    const int mblock = (L >> 3) % NB;
    const int rowbase = mblock * MROWS;

    const int T    = (N + 63) >> 6;           // total 64-col iterations
    const int base = T / NSPLIT;
    const int remu = T % NSPLIT;
    const int it0  = split * base + min(split, remu);
    const int cnt  = base + (split < remu ? 1 : 0);
    const bool maskedLast = (it0 + cnt == T) && ((N & 63) != 0);
    const int nfull = cnt - (maskedLast ? 1 : 0);

    __shared__ short ldsB[4][2][1024];   // [wave][buf][16 cols * 64 shorts]
    __shared__ float ldsE[4][2][16];     // [wave][buf][16 cols]
    __shared__ float red[4][MROWS];

    // A fragments (bf16, pre-scaled by -2q): row = lane&15, k = 8*(lane>>4)+i
    short8 afrag[8][2];
    #pragma unroll
    for (int rf = 0; rf < 8; ++rf) {
        const short* p = xb + (size_t)(rowbase + rf*16 + l15) * 64 + kq * 8;
        afrag[rf][0] = *(const short8*)(p);
        afrag[rf][1] = *(const short8*)(p + 32);
    }

    const f32x4 zero4 = {0.f, 0.f, 0.f, 0.f};

    float s[8][4];
    #pragma unroll
    for (int rf = 0; rf < 8; ++rf)
        #pragma unroll
        for (int r = 0; r < 4; ++r) s[rf][r] = 0.f;

    f32x4 acc[8];

    // Stage iteration kabs (absolute within this split: col base = (it0+kabs)*64
    // + wave*16) into buf c. 3 vmem ops: 2x 16B B-tile + 1x 4B Eq.
    auto STAGE = [&](int kabs, int c) {
        const int colb = (it0 + kabs) * 64 + wave * 16;
        #pragma unroll
        for (int i = 0; i < 2; ++i) {
            const int colr = i*8 + (lane >> 3);      // 0..15 within wave's 16
            const int seg  = lane & 7;               // 16B segment 0..7
            const char* src = (const char*)Xb
                + (((size_t)(colb + colr)) << 7)
                + (((seg ^ (colr & 7))) << 4);       // pre-swizzled source
            __builtin_amdgcn_global_load_lds(
                (const AS1 char*)src,
                (AS3 char*)((char*)&ldsB[wave][c][0] + i * 1024),
                16, 0, 0);
        }
        if (lane < 16) {
            __builtin_amdgcn_global_load_lds(
                (const AS1 char*)(const char*)(Eq + colb + lane),
                (AS3 char*)(char*)&ldsE[wave][c][0],
                4, 0, 0);
        }
    };

    auto MFMAPH = [&](short8 B0, short8 B1) {
        #pragma unroll
        for (int rf = 0; rf < 8; ++rf) {
            f32x4 a = __builtin_amdgcn_mfma_f32_16x16x32_bf16(afrag[rf][0], B0, zero4, 0, 0, 0);
            acc[rf]  = __builtin_amdgcn_mfma_f32_16x16x32_bf16(afrag[rf][1], B1, a, 0, 0, 0);
        }
    };
    auto EXPPH = [&](float E) {
        #pragma unroll
        for (int rf = 0; rf < 8; ++rf)
            #pragma unroll
            for (int r = 0; r < 4; ++r)
                s[rf][r] = fmaf(E, __builtin_amdgcn_exp2f(acc[rf][r]), s[rf][r]);
    };

    auto ITER = [&](int kabs, int c) {
        // wait for THIS iter's stage; leave next iter's 3 ops in flight
        if (kabs + 1 < nfull) asm volatile("s_waitcnt vmcnt(3)" ::: "memory");
        else                  asm volatile("s_waitcnt vmcnt(0)" ::: "memory");
        __builtin_amdgcn_sched_barrier(0);

        const char* bb = (const char*)&ldsB[wave][c][0];
        short8 B0 = *(const short8*)(bb + l15*128 + ((kq       ^ (l15 & 7)) << 4));
        short8 B1 = *(const short8*)(bb + l15*128 + (((kq + 4) ^ (l15 & 7)) << 4));
        float  E  = ldsE[wave][c][l15];

        MFMAPH(B0, B1);

        // all ds_reads complete before the async stage can overwrite this buf
        asm volatile("s_waitcnt lgkmcnt(0)" ::: "memory");
        __builtin_amdgcn_sched_barrier(0);
        if (kabs + 2 < nfull) STAGE(kabs + 2, c);

        EXPPH(E);
    };

    if (nfull >= 1) STAGE(0, 0);
    if (nfull >= 2) STAGE(1, 1);
    int k = 0;
    for (; k + 1 < nfull; k += 2) {
        ITER(k, 0);
        ITER(k + 1, 1);
    }
    if (k < nfull) ITER(k, 0);

    // masked tail (single global-last iteration, if ragged) — direct loads
    if (maskedLast) {
        asm volatile("s_waitcnt vmcnt(0)" ::: "memory");
        const int col = (it0 + cnt - 1)*64 + wave*16 + l15;
        const int c   = min(col, N - 1);
        const short* p = Xb + (size_t)c * 64 + kq * 8;
        short8 B0 = *(const short8*)(p);
        short8 B1 = *(const short8*)(p + 32);
        float  E  = (col < N) ? Eq[c] : 0.f;
        MFMAPH(B0, B1);
        EXPPH(E);
    }

    // reduce across the 16 lanes holding cols
    float t[8][4];
    #pragma unroll
    for (int rf = 0; rf < 8; ++rf)
        #pragma unroll
        for (int r = 0; r < 4; ++r) {
            float v = s[rf][r];
            v += __shfl_xor(v, 1);
            v += __shfl_xor(v, 2);
            v += __shfl_xor(v, 4);
            v += __shfl_xor(v, 8);
            t[rf][r] = v;
        }

    if (l15 == 0) {
        #pragma unroll
        for (int rf = 0; rf < 8; ++rf)
            #pragma unroll
            for (int r = 0; r < 4; ++r)
                red[wave][rf*16 + kq*4 + r] = t[rf][r];
    }
    __syncthreads();
    if (tid < MROWS) {
        partial[(size_t)split * M + rowbase + tid] =
            red[0][tid] + red[1][tid] + red[2][tid] + red[3][tid];
    }
}

__global__ __launch_bounds__(256) void kde_combine2(
    const float* __restrict__ ws, const float* __restrict__ x2q,
    float* __restrict__ out, int M, int nsplit, float coeff)
{
    int i = blockIdx.x * 256 + threadIdx.x;
    if (i < M) {
        float t = 0.f;
        for (int s = 0; s < nsplit; ++s) t += ws[(size_t)s * M + i];
        out[i] = fmaf(0.6931471805599453f, x2q[i], logf(t) + coeff);
    }
}

// ---------------------------------------------------------------------------
// Fallback fused fp32 path (only if ws too small or M not tile-divisible).
// ---------------------------------------------------------------------------
__global__ __launch_bounds__(256) void kde_main_fb(
    const float* __restrict__ x, const float* __restrict__ Xg,
    const float* __restrict__ bw, float* __restrict__ ws,
    float* __restrict__ out, int M, int N, int nsplit, float coeff)
{
    const int tid  = threadIdx.x;
    const int lane = tid & 63;
    const int wave = tid >> 6;
    const int l15  = lane & 15;
    const int kq   = lane >> 4;
    const int rowbase = blockIdx.x * 64;
    const int split   = blockIdx.y;
    const int chunk   = (N + nsplit - 1) / nsplit;
    const int colstart = split * chunk;
    const int colend   = min(colstart + chunk, N);

    __shared__ float lds_x2[64];
    __shared__ float red[4][64];

    if (tid < 64) {
        const float* xp = x + (size_t)(rowbase + tid) * 64;
        float ssum = 0.f;
        #pragma unroll
        for (int k = 0; k < 16; ++k) {
            float4 v = ((const float4*)xp)[k];
            ssum += v.x*v.x + v.y*v.y + v.z*v.z + v.w*v.w;
        }
        lds_x2[tid] = ssum;
    }

    short8 afrag[4][2];
    #pragma unroll
    for (int rf = 0; rf < 4; ++rf) {
        const float* xp = x + (size_t)(rowbase + rf*16 + l15) * 64;
        #pragma unroll
        for (int kf = 0; kf < 2; ++kf) {
            const float* p = xp + kf*32 + kq*8;
            float4 v0 = ((const float4*)p)[0];
            float4 v1 = ((const float4*)p)[1];
            short8 a;
            a[0]=f2bf(v0.x); a[1]=f2bf(v0.y); a[2]=f2bf(v0.z); a[3]=f2bf(v0.w);
            a[4]=f2bf(v1.x); a[5]=f2bf(v1.y); a[6]=f2bf(v1.z); a[7]=f2bf(v1.w);
            afrag[rf][kf] = a;
        }
    }
    __syncthreads();

    float xa[4][4];
    #pragma unroll
    for (int rf = 0; rf < 4; ++rf)
        #pragma unroll
        for (int r = 0; r < 4; ++r)
            xa[rf][r] = lds_x2[rf*16 + kq*4 + r];

    const float b = bw[0];
    const float q = -1.4426950408889634f / (2.f * b * b);

    float s[4][4];
    #pragma unroll
    for (int rf = 0; rf < 4; ++rf)
        #pragma unroll
        for (int r = 0; r < 4; ++r) s[rf][r] = 0.f;

    const int span  = colend - colstart;
    const int niter = (span + 63) / 64;

    for (int it = 0; it < niter; ++it) {
        const int col  = colstart + it*64 + wave*16 + l15;
        const int colc = min(col, N - 1);
        const bool valid = (col < colend);

        const float* Xp = Xg + (size_t)colc * 64;
        float4 v0 = ((const float4*)(Xp + kq*8))[0];
        float4 v1 = ((const float4*)(Xp + kq*8))[1];
        float4 v2 = ((const float4*)(Xp + 32 + kq*8))[0];
        float4 v3 = ((const float4*)(Xp + 32 + kq*8))[1];

        float pa = v0.x*v0.x + v0.y*v0.y + v0.z*v0.z + v0.w*v0.w
                 + v1.x*v1.x + v1.y*v1.y + v1.z*v1.z + v1.w*v1.w
                 + v2.x*v2.x + v2.y*v2.y + v2.z*v2.z + v2.w*v2.w
                 + v3.x*v3.x + v3.y*v3.y + v3.z*v3.z + v3.w*v3.w;
        pa += __shfl_xor(pa, 16);
        pa += __shfl_xor(pa, 32);

        short8 bb0, bb1;
        bb0[0]=f2bf(v0.x); bb0[1]=f2bf(v0.y); bb0[2]=f2bf(v0.z); bb0[3]=f2bf(v0.w);
        bb0[4]=f2bf(v1.x); bb0[5]=f2bf(v1.y); bb0[6]=f2bf(v1.z); bb0[7]=f2bf(v1.w);
        bb1[0]=f2bf(v2.x); bb1[1]=f2bf(v2.y); bb1[2]=f2bf(v2.z); bb1[3]=f2bf(v2.w);
        bb1[4]=f2bf(v3.x); bb1[5]=f2bf(v3.y); bb1[6]=f2bf(v3.z); bb1[7]=f2bf(v3.w);

        #pragma unroll
        for (int rf = 0; rf < 4; ++rf) {
            f32x4 acc = {0.f, 0.f, 0.f, 0.f};
            acc = __builtin_amdgcn_mfma_f32_16x16x32_bf16(afrag[rf][0], bb0, acc, 0, 0, 0);
            acc = __builtin_amdgcn_mfma_f32_16x16x32_bf16(afrag[rf][1], bb1, acc, 0, 0, 0);
            #pragma unroll
            for (int r = 0; r < 4; ++r) {
                float d2 = fmaxf(xa[rf][r] + pa - 2.f*acc[r], 0.f);
                float e = valid ? __builtin_amdgcn_exp2f(d2 * q) : 0.f;
                s[rf][r] += e;
            }
        }
    }

    #pragma unroll
    for (int rf = 0; rf < 4; ++rf)
        #pragma unroll
        for (int r = 0; r < 4; ++r) {
            float v = s[rf][r];
            v += __shfl_xor(v, 1);
            v += __shfl_xor(v, 2);
            v += __shfl_xor(v, 4);
            v += __shfl_xor(v, 8);
            s[rf][r] = v;
        }

    __syncthreads();
    if (l15 == 0) {
        #pragma unroll
        for (int rf = 0; rf < 4; ++rf)
            #pragma unroll
            for (int r = 0; r < 4; ++r)
                red[wave][rf*16 + kq*4 + r] = s[rf][r];
    }
    __syncthreads();

    if (tid < 64) {
        float tot = red[0][tid] + red[1][tid] + red[2][tid] + red[3][tid];
        if (nsplit == 1) out[rowbase + tid] = logf(tot) + coeff;
        else             ws[(size_t)split * M + rowbase + tid] = tot;
    }
}

__global__ __launch_bounds__(256) void kde_combine_fb(
    const float* __restrict__ ws, float* __restrict__ out,
    int M, int nsplit, float coeff)
{
    int i = blockIdx.x * 256 + threadIdx.x;
    if (i < M) {
        float t = 0.f;
        for (int s = 0; s < nsplit; ++s) t += ws[(size_t)s * M + i];
        out[i] = logf(t) + coeff;
    }
}

extern "C" void kernel_launch(void* const* d_in, const int* in_sizes, int n_in,
                              void* d_out, int out_size, void* d_ws, size_t ws_size,
                              hipStream_t stream) {
    const float* x  = (const float*)d_in[0];
    const float* Xg = (const float*)d_in[1];
    const float* bw = (const float*)d_in[2];
    float* out = (float*)d_out;

    const int M = in_sizes[0] / 64;
    const int N = in_sizes[1] / 64;
    const float coeff = -logf((float)N) - logf(2.f * (float)M_PI) * 32.f;

    auto align256 = [](size_t v) { return (v + 255) & ~(size_t)255; };
    const size_t szXb   = align256((size_t)N * 64 * sizeof(short));
    const size_t szxb   = align256((size_t)M * 64 * sizeof(short));
    const size_t szEq   = align256((size_t)N * sizeof(float));
    const size_t szx2q  = align256((size_t)M * sizeof(float));
    const size_t szPart = align256((size_t)NSPLIT * M * sizeof(float));
    const size_t need   = szXb + szxb + szEq + szx2q + szPart;

    if (ws_size >= need && (M % MROWS) == 0) {
        char* w = (char*)d_ws;
        short* Xb   = (short*)(w);
        short* xb   = (short*)(w + szXb);
        float* Eq   = (float*)(w + szXb + szxb);
        float* x2q  = (float*)(w + szXb + szxb + szEq);
        float* part = (float*)(w + szXb + szxb + szEq + szx2q);

        const int totalRows = M + N;
        kde_prep<<<(totalRows * 8 + 255) / 256, 256, 0, stream>>>(
            x, Xg, bw, Xb, Eq, xb, x2q, M, N);

        const int NB = M / MROWS;
        kde_main10<<<NB * NSPLIT, 256, 0, stream>>>(Xb, Eq, xb, part, M, N, NB);

        kde_combine2<<<(M + 255) / 256, 256, 0, stream>>>(part, x2q, out, M, NSPLIT, coeff);
    } else {
        int nsplit = 8;
        if (ws_size < (size_t)nsplit * M * sizeof(float)) nsplit = 1;
        dim3 grid(M / 64, nsplit);
        kde_main_fb<<<grid, 256, 0, stream>>>(x, Xg, bw, (float*)d_ws, out, M, N, nsplit, coeff);
        if (nsplit > 1)
            kde_combine_fb<<<(M + 255) / 256, 256, 0, stream>>>((const float*)d_ws, out, M, nsplit, coeff);
    }
}

// Round 12
// 58.989 us; speedup vs baseline: 1.5005x; 1.5005x over previous
//
#include <hip/hip_runtime.h>
#include <hip/hip_bf16.h>
#include <math.h>

#define NSPLIT 32          // divisible by 8 for the XCD swizzle
#define MROWS  128

typedef __attribute__((ext_vector_type(8))) short short8;
typedef __attribute__((ext_vector_type(4))) float f32x4;

#define AS1 __attribute__((address_space(1)))
#define AS3 __attribute__((address_space(3)))

__device__ __forceinline__ short f2bf(float f) {
    __hip_bfloat16 h = __float2bfloat16(f);
    return __builtin_bit_cast(short, h);
}

// ---------------------------------------------------------------------------
// Preprocess:
//   X rows -> Xb bf16 (unscaled)  + Eq[col] = exp2(q*||X||^2)  (f32)
//   x rows -> xb bf16 scaled by -2q + x2q[row] = q*||x||^2     (f32)
// q = -log2(e)/(2 b^2).  exp(-d2/(2b^2)) = exp2(q*x2) * Eq[col] * exp2((-2q x)·X)
// ---------------------------------------------------------------------------
__global__ __launch_bounds__(256) void kde_prep(
    const float* __restrict__ x, const float* __restrict__ Xg,
    const float* __restrict__ bw,
    short* __restrict__ Xb, float* __restrict__ Eq,
    short* __restrict__ xb, float* __restrict__ x2q, int M, int N)
{
    const int gid = blockIdx.x * 256 + threadIdx.x;
    const int row = gid >> 3;
    const int sub = gid & 7;
    if (row >= M + N) return;

    const float b = bw[0];
    const float q = -1.4426950408889634f / (2.f * b * b);
    const float s2q = -2.f * q;

    const float* src;
    short* dst;
    float sc;
    if (row < N) { src = Xg + (size_t)row * 64;     dst = Xb + (size_t)row * 64;     sc = 1.f; }
    else         { src = x  + (size_t)(row-N) * 64; dst = xb + (size_t)(row-N) * 64; sc = s2q; }

    float4 v0 = ((const float4*)(src + sub * 8))[0];
    float4 v1 = ((const float4*)(src + sub * 8))[1];

    float ss = v0.x*v0.x + v0.y*v0.y + v0.z*v0.z + v0.w*v0.w
             + v1.x*v1.x + v1.y*v1.y + v1.z*v1.z + v1.w*v1.w;
    ss += __shfl_xor(ss, 1);
    ss += __shfl_xor(ss, 2);
    ss += __shfl_xor(ss, 4);

    short8 o;
    o[0]=f2bf(v0.x*sc); o[1]=f2bf(v0.y*sc); o[2]=f2bf(v0.z*sc); o[3]=f2bf(v0.w*sc);
    o[4]=f2bf(v1.x*sc); o[5]=f2bf(v1.y*sc); o[6]=f2bf(v1.z*sc); o[7]=f2bf(v1.w*sc);
    *(short8*)(dst + sub * 8) = o;

    if (sub == 0) {
        if (row < N) Eq[row] = exp2f(ss * q);
        else         x2q[row - N] = ss * q;
    }
}

// ---------------------------------------------------------------------------
// Main (round 12): block = 128 rows x 64 cols/iter; wave w owns rows
// [w*32, w*32+32) x ALL 64 cols (2 rf frags -> ~100 live regs -> 4 waves/SIMD
// with launch_bounds(256,4); r9's spill trap avoided: live state actually fits).
//
// B (8KB) + per-wave Eq copies staged block-cooperatively into a RING-3 LDS
// buffer via global_load_lds (3 ops/wave/iter), hand-counted s_waitcnt
// vmcnt(3), and ONE raw s_barrier per iter (ring-3 removes the WAR barrier;
// raw barrier avoids __syncthreads' vmcnt(0) drain). Stage of iter k+1 stays
// in flight across compute of iter k.
//
// The 4 waves/SIMD come from 4 DIFFERENT blocks (1 wave per block per SIMD),
// so their barriers are independent -> phases desync -> MFMA and trans pipes
// stay fed. LDS swizzle: store B[cc][seg^(cc&7)] (via pre-swizzled global
// source, r11-verified); ds_read applies the same XOR -> 2-way conflicts only.
//
// XCD swizzle: split=(L&7)+8*(L/(8*NB)), mblock=(L>>3)%NB; per-XCD working
// set = 4 chunks (~800 KB) -> L2-resident.
// ---------------------------------------------------------------------------
__global__ __launch_bounds__(256, 4) void kde_main11(
    const short* __restrict__ Xb, const float* __restrict__ Eq,
    const short* __restrict__ xb,
    float* __restrict__ partial, int M, int N, int NB)
{
    const int tid  = threadIdx.x;
    const int lane = tid & 63;
    const int wave = tid >> 6;
    const int l15  = lane & 15;
    const int kq   = lane >> 4;

    const int L      = blockIdx.x;
    const int split  = (L & 7) + 8 * (L / (8 * NB));
    const int mblock = (L >> 3) % NB;
    const int rowbase = mblock * MROWS;

    const int T    = (N + 63) >> 6;           // total 64-col iterations
    const int base = T / NSPLIT;
    const int remu = T % NSPLIT;
    const int it0  = split * base + min(split, remu);
    const int cnt  = base + (split < remu ? 1 : 0);
    const bool maskedLast = (it0 + cnt == T) && ((N & 63) != 0);
    const int nfull = cnt - (maskedLast ? 1 : 0);

    __shared__ short ldsB[3][4096];      // ring-3: 64 cols x 64 shorts (8KB each)
    __shared__ float ldsE[3][4][64];     // per-wave Eq copies

    // A fragments: wave owns rows rowbase + wave*32 + rf*16 + (lane&15)
    short8 af00, af01, af10, af11;
    {
        const short* p0 = xb + (size_t)(rowbase + wave*32 +      l15) * 64 + kq * 8;
        const short* p1 = xb + (size_t)(rowbase + wave*32 + 16 + l15) * 64 + kq * 8;
        af00 = *(const short8*)(p0);
        af01 = *(const short8*)(p0 + 32);
        af10 = *(const short8*)(p1);
        af11 = *(const short8*)(p1 + 32);
    }

    const f32x4 zero4 = {0.f, 0.f, 0.f, 0.f};

    float s0[4][4], s1[4][4];            // [cg][r]
    #pragma unroll
    for (int cg = 0; cg < 4; ++cg)
        #pragma unroll
        for (int r = 0; r < 4; ++r) { s0[cg][r] = 0.f; s1[cg][r] = 0.f; }

    // Stage iter kabs into ring slot c: 2x 16B B-tile + 1x 4B Eq per wave.
    // Source segment pre-swizzled so LDS holds B[cc][seg ^ (cc&7)].
    auto STAGE = [&](int kabs, int c) {
        const int colb = (it0 + kabs) * 64;
        #pragma unroll
        for (int i = 0; i < 2; ++i) {
            const int crel = wave*16 + i*8 + (lane >> 3);
            const char* src = (const char*)Xb + (((size_t)(colb + crel)) << 7)
                              + ((size_t)((lane & 7) ^ (lane >> 3)) << 4);
            __builtin_amdgcn_global_load_lds(
                (const AS1 char*)src,
                (AS3 char*)((char*)ldsB[c] + wave*2048 + i*1024), 16, 0, 0);
        }
        __builtin_amdgcn_global_load_lds(
            (const AS1 char*)(const char*)(Eq + colb + lane),
            (AS3 char*)((char*)&ldsE[c][wave][0]), 4, 0, 0);
    };

    auto COMPUTE = [&](int c) {
        const char* bb = (const char*)ldsB[c];
        #pragma unroll
        for (int cg = 0; cg < 4; ++cg) {
            const int cc = cg*16 + l15;
            const int sw = l15 & 7;
            short8 B0 = *(const short8*)(bb + cc*128 + ((kq       ^ sw) << 4));
            short8 B1 = *(const short8*)(bb + cc*128 + (((kq + 4) ^ sw) << 4));
            f32x4 a0 = __builtin_amdgcn_mfma_f32_16x16x32_bf16(af00, B0, zero4, 0, 0, 0);
            a0 = __builtin_amdgcn_mfma_f32_16x16x32_bf16(af01, B1, a0, 0, 0, 0);
            f32x4 a1 = __builtin_amdgcn_mfma_f32_16x16x32_bf16(af10, B0, zero4, 0, 0, 0);
            a1 = __builtin_amdgcn_mfma_f32_16x16x32_bf16(af11, B1, a1, 0, 0, 0);
            const float E = ldsE[c][wave][cc];
            #pragma unroll
            for (int r = 0; r < 4; ++r)
                s0[cg][r] = fmaf(E, __builtin_amdgcn_exp2f(a0[r]), s0[cg][r]);
            #pragma unroll
            for (int r = 0; r < 4; ++r)
                s1[cg][r] = fmaf(E, __builtin_amdgcn_exp2f(a1[r]), s1[cg][r]);
        }
    };

    // ring-3 pipeline, 1 barrier/iter, stage k+1 in flight across compute k
    STAGE(0, 0);
    int cur = 0, nxt = 1;
    for (int k = 0; k < nfull; ++k) {
        if (k + 1 < nfull) STAGE(k + 1, nxt);
        __builtin_amdgcn_sched_barrier(0);
        if (k + 1 < nfull) asm volatile("s_waitcnt vmcnt(3)" ::: "memory");
        else               asm volatile("s_waitcnt vmcnt(0)" ::: "memory");
        __builtin_amdgcn_sched_barrier(0);
        __builtin_amdgcn_s_barrier();
        __builtin_amdgcn_sched_barrier(0);
        COMPUTE(cur);
        cur = (cur == 2) ? 0 : cur + 1;
        nxt = (nxt == 2) ? 0 : nxt + 1;
    }

    // masked tail (single ragged 64-col iteration): direct global loads
    if (maskedLast) {
        const int tb = (it0 + cnt - 1) * 64;
        #pragma unroll
        for (int cg = 0; cg < 4; ++cg) {
            const int col = tb + cg*16 + l15;
            const int cl  = min(col, N - 1);
            const short* p = Xb + (size_t)cl * 64 + kq * 8;
            short8 B0 = *(const short8*)(p);
            short8 B1 = *(const short8*)(p + 32);
            f32x4 a0 = __builtin_amdgcn_mfma_f32_16x16x32_bf16(af00, B0, zero4, 0, 0, 0);
            a0 = __builtin_amdgcn_mfma_f32_16x16x32_bf16(af01, B1, a0, 0, 0, 0);
            f32x4 a1 = __builtin_amdgcn_mfma_f32_16x16x32_bf16(af10, B0, zero4, 0, 0, 0);
            a1 = __builtin_amdgcn_mfma_f32_16x16x32_bf16(af11, B1, a1, 0, 0, 0);
            const float E = (col < N) ? Eq[cl] : 0.f;
            #pragma unroll
            for (int r = 0; r < 4; ++r)
                s0[cg][r] = fmaf(E, __builtin_amdgcn_exp2f(a0[r]), s0[cg][r]);
            #pragma unroll
            for (int r = 0; r < 4; ++r)
                s1[cg][r] = fmaf(E, __builtin_amdgcn_exp2f(a1[r]), s1[cg][r]);
        }
    }

    // reduce: sum col-groups, then over the 16 lanes holding cols; each wave
    // owns its 32 rows exclusively -> direct global write, no cross-wave LDS.
    #pragma unroll
    for (int rf = 0; rf < 2; ++rf) {
        #pragma unroll
        for (int r = 0; r < 4; ++r) {
            float v = rf == 0 ? (s0[0][r] + s0[1][r] + s0[2][r] + s0[3][r])
                              : (s1[0][r] + s1[1][r] + s1[2][r] + s1[3][r]);
            v += __shfl_xor(v, 1);
            v += __shfl_xor(v, 2);
            v += __shfl_xor(v, 4);
            v += __shfl_xor(v, 8);
            if (l15 == 0)
                partial[(size_t)split * M + rowbase + wave*32 + rf*16 + kq*4 + r] = v;
        }
    }
}

__global__ __launch_bounds__(256) void kde_combine2(
    const float* __restrict__ ws, const float* __restrict__ x2q,
    float* __restrict__ out, int M, int nsplit, float coeff)
{
    int i = blockIdx.x * 256 + threadIdx.x;
    if (i < M) {
        float t = 0.f;
        for (int s = 0; s < nsplit; ++s) t += ws[(size_t)s * M + i];
        out[i] = fmaf(0.6931471805599453f, x2q[i], logf(t) + coeff);
    }
}

// ---------------------------------------------------------------------------
// Fallback fused fp32 path (only if ws too small or M not tile-divisible).
// ---------------------------------------------------------------------------
__global__ __launch_bounds__(256) void kde_main_fb(
    const float* __restrict__ x, const float* __restrict__ Xg,
    const float* __restrict__ bw, float* __restrict__ ws,
    float* __restrict__ out, int M, int N, int nsplit, float coeff)
{
    const int tid  = threadIdx.x;
    const int lane = tid & 63;
    const int wave = tid >> 6;
    const int l15  = lane & 15;
    const int kq   = lane >> 4;
    const int rowbase = blockIdx.x * 64;
    const int split   = blockIdx.y;
    const int chunk   = (N + nsplit - 1) / nsplit;
    const int colstart = split * chunk;
    const int colend   = min(colstart + chunk, N);

    __shared__ float lds_x2[64];
    __shared__ float red[4][64];

    if (tid < 64) {
        const float* xp = x + (size_t)(rowbase + tid) * 64;
        float ssum = 0.f;
        #pragma unroll
        for (int k = 0; k < 16; ++k) {
            float4 v = ((const float4*)xp)[k];
            ssum += v.x*v.x + v.y*v.y + v.z*v.z + v.w*v.w;
        }
        lds_x2[tid] = ssum;
    }

    short8 afrag[4][2];
    #pragma unroll
    for (int rf = 0; rf < 4; ++rf) {
        const float* xp = x + (size_t)(rowbase + rf*16 + l15) * 64;
        #pragma unroll
        for (int kf = 0; kf < 2; ++kf) {
            const float* p = xp + kf*32 + kq*8;
            float4 v0 = ((const float4*)p)[0];
            float4 v1 = ((const float4*)p)[1];
            short8 a;
            a[0]=f2bf(v0.x); a[1]=f2bf(v0.y); a[2]=f2bf(v0.z); a[3]=f2bf(v0.w);
            a[4]=f2bf(v1.x); a[5]=f2bf(v1.y); a[6]=f2bf(v1.z); a[7]=f2bf(v1.w);
            afrag[rf][kf] = a;
        }
    }
    __syncthreads();

    float xa[4][4];
    #pragma unroll
    for (int rf = 0; rf < 4; ++rf)
        #pragma unroll
        for (int r = 0; r < 4; ++r)
            xa[rf][r] = lds_x2[rf*16 + kq*4 + r];

    const float b = bw[0];
    const float q = -1.4426950408889634f / (2.f * b * b);

    float s[4][4];
    #pragma unroll
    for (int rf = 0; rf < 4; ++rf)
        #pragma unroll
        for (int r = 0; r < 4; ++r) s[rf][r] = 0.f;

    const int span  = colend - colstart;
    const int niter = (span + 63) / 64;

    for (int it = 0; it < niter; ++it) {
        const int col  = colstart + it*64 + wave*16 + l15;
        const int colc = min(col, N - 1);
        const bool valid = (col < colend);

        const float* Xp = Xg + (size_t)colc * 64;
        float4 v0 = ((const float4*)(Xp + kq*8))[0];
        float4 v1 = ((const float4*)(Xp + kq*8))[1];
        float4 v2 = ((const float4*)(Xp + 32 + kq*8))[0];
        float4 v3 = ((const float4*)(Xp + 32 + kq*8))[1];

        float pa = v0.x*v0.x + v0.y*v0.y + v0.z*v0.z + v0.w*v0.w
                 + v1.x*v1.x + v1.y*v1.y + v1.z*v1.z + v1.w*v1.w
                 + v2.x*v2.x + v2.y*v2.y + v2.z*v2.z + v2.w*v2.w
                 + v3.x*v3.x + v3.y*v3.y + v3.z*v3.z + v3.w*v3.w;
        pa += __shfl_xor(pa, 16);
        pa += __shfl_xor(pa, 32);

        short8 bb0, bb1;
        bb0[0]=f2bf(v0.x); bb0[1]=f2bf(v0.y); bb0[2]=f2bf(v0.z); bb0[3]=f2bf(v0.w);
        bb0[4]=f2bf(v1.x); bb0[5]=f2bf(v1.y); bb0[6]=f2bf(v1.z); bb0[7]=f2bf(v1.w);
        bb1[0]=f2bf(v2.x); bb1[1]=f2bf(v2.y); bb1[2]=f2bf(v2.z); bb1[3]=f2bf(v2.w);
        bb1[4]=f2bf(v3.x); bb1[5]=f2bf(v3.y); bb1[6]=f2bf(v3.z); bb1[7]=f2bf(v3.w);

        #pragma unroll
        for (int rf = 0; rf < 4; ++rf) {
            f32x4 acc = {0.f, 0.f, 0.f, 0.f};
            acc = __builtin_amdgcn_mfma_f32_16x16x32_bf16(afrag[rf][0], bb0, acc, 0, 0, 0);
            acc = __builtin_amdgcn_mfma_f32_16x16x32_bf16(afrag[rf][1], bb1, acc, 0, 0, 0);
            #pragma unroll
            for (int r = 0; r < 4; ++r) {
                float d2 = fmaxf(xa[rf][r] + pa - 2.f*acc[r], 0.f);
                float e = valid ? __builtin_amdgcn_exp2f(d2 * q) : 0.f;
                s[rf][r] += e;
            }
        }
    }

    #pragma unroll
    for (int rf = 0; rf < 4; ++rf)
        #pragma unroll
        for (int r = 0; r < 4; ++r) {
            float v = s[rf][r];
            v += __shfl_xor(v, 1);
            v += __shfl_xor(v, 2);
            v += __shfl_xor(v, 4);
            v += __shfl_xor(v, 8);
            s[rf][r] = v;
        }

    __syncthreads();
    if (l15 == 0) {
        #pragma unroll
        for (int rf = 0; rf < 4; ++rf)
            #pragma unroll
            for (int r = 0; r < 4; ++r)
                red[wave][rf*16 + kq*4 + r] = s[rf][r];
    }
    __syncthreads();

    if (tid < 64) {
        float tot = red[0][tid] + red[1][tid] + red[2][tid] + red[3][tid];
        if (nsplit == 1) out[rowbase + tid] = logf(tot) + coeff;
        else             ws[(size_t)split * M + rowbase + tid] = tot;
    }
}

__global__ __launch_bounds__(256) void kde_combine_fb(
    const float* __restrict__ ws, float* __restrict__ out,
    int M, int nsplit, float coeff)
{
    int i = blockIdx.x * 256 + threadIdx.x;
    if (i < M) {
        float t = 0.f;
        for (int s = 0; s < nsplit; ++s) t += ws[(size_t)s * M + i];
        out[i] = logf(t) + coeff;
    }
}

extern "C" void kernel_launch(void* const* d_in, const int* in_sizes, int n_in,
                              void* d_out, int out_size, void* d_ws, size_t ws_size,
                              hipStream_t stream) {
    const float* x  = (const float*)d_in[0];
    const float* Xg = (const float*)d_in[1];
    const float* bw = (const float*)d_in[2];
    float* out = (float*)d_out;

    const int M = in_sizes[0] / 64;
    const int N = in_sizes[1] / 64;
    const float coeff = -logf((float)N) - logf(2.f * (float)M_PI) * 32.f;

    auto align256 = [](size_t v) { return (v + 255) & ~(size_t)255; };
    const size_t szXb   = align256((size_t)N * 64 * sizeof(short));
    const size_t szxb   = align256((size_t)M * 64 * sizeof(short));
    const size_t szEq   = align256((size_t)N * sizeof(float));
    const size_t szx2q  = align256((size_t)M * sizeof(float));
    const size_t szPart = align256((size_t)NSPLIT * M * sizeof(float));
    const size_t need   = szXb + szxb + szEq + szx2q + szPart;

    if (ws_size >= need && (M % MROWS) == 0) {
        char* w = (char*)d_ws;
        short* Xb   = (short*)(w);
        short* xb   = (short*)(w + szXb);
        float* Eq   = (float*)(w + szXb + szxb);
        float* x2q  = (float*)(w + szXb + szxb + szEq);
        float* part = (float*)(w + szXb + szxb + szEq + szx2q);

        const int totalRows = M + N;
        kde_prep<<<(totalRows * 8 + 255) / 256, 256, 0, stream>>>(
            x, Xg, bw, Xb, Eq, xb, x2q, M, N);

        const int NB = M / MROWS;
        kde_main11<<<NB * NSPLIT, 256, 0, stream>>>(Xb, Eq, xb, part, M, N, NB);

        kde_combine2<<<(M + 255) / 256, 256, 0, stream>>>(part, x2q, out, M, NSPLIT, coeff);
    } else {
        int nsplit = 8;
        if (ws_size < (size_t)nsplit * M * sizeof(float)) nsplit = 1;
        dim3 grid(M / 64, nsplit);
        kde_main_fb<<<grid, 256, 0, stream>>>(x, Xg, bw, (float*)d_ws, out, M, N, nsplit, coeff);
        if (nsplit > 1)
            kde_combine_fb<<<(M + 255) / 256, 256, 0, stream>>>((const float*)d_ws, out, M, nsplit, coeff);
    }
}